// Round 1
// baseline (677.140 us; speedup 1.0000x reference)
//
#include <hip/hip_runtime.h>
#include <math.h>

#define TOKENS 16384
#define HIDDEN 4096
#define NEXP   64
#define TOPK   8

#define BK  32
#define TM  64
#define LDT 68   // padded LDS row stride (floats): 16B-aligned rows, conflict-benign

// ---------------- Kernel 1: tiled f32 GEMM -> partial logits ----------------
// grid: (TOKENS/TM) x ksplit, block 256.
// Each block: 64 tokens x 64 experts over K-range [bk*kspan, +kspan).
// Per-thread 4 tokens x 4 experts; per-32-K-tile temp accumulator for
// blocked (BLAS-grade) f32 accumulation noise.
__global__ __launch_bounds__(256, 2) void router_gemm(
    const float* __restrict__ hs, const float* __restrict__ w,
    float* __restrict__ partial, int ksplit)
{
    __shared__ float hsT[BK][LDT];
    __shared__ float wT[BK][LDT];

    const int tid = threadIdx.x;
    const int bt  = blockIdx.x;           // token tile
    const int bk  = blockIdx.y;           // K split index
    const int kspan  = HIDDEN / ksplit;
    const int k0base = bk * kspan;
    const int tg = tid & 15;              // token group (4 tokens)
    const int eg = tid >> 4;              // expert group (4 experts)

    float acc[4][4] = {{0.f, 0.f, 0.f, 0.f}, {0.f, 0.f, 0.f, 0.f},
                       {0.f, 0.f, 0.f, 0.f}, {0.f, 0.f, 0.f, 0.f}};

    const int ntiles = kspan / BK;
    for (int tile = 0; tile < ntiles; ++tile) {
        const int k0 = k0base + tile * BK;
        // stage hs tile (64 tok x 32 k) and w tile (64 exp x 32 k), transposed
        #pragma unroll
        for (int p = 0; p < 2; ++p) {
            const int id  = tid + p * 256;
            const int row = id >> 3;             // 0..63
            const int c4  = (id & 7) << 2;       // 0,4,...,28
            float4 hv = *(const float4*)&hs[(size_t)(bt * TM + row) * HIDDEN + k0 + c4];
            hsT[c4 + 0][row] = hv.x;
            hsT[c4 + 1][row] = hv.y;
            hsT[c4 + 2][row] = hv.z;
            hsT[c4 + 3][row] = hv.w;
            float4 wv = *(const float4*)&w[(size_t)row * HIDDEN + k0 + c4];
            wT[c4 + 0][row] = wv.x;
            wT[c4 + 1][row] = wv.y;
            wT[c4 + 2][row] = wv.z;
            wT[c4 + 3][row] = wv.w;
        }
        __syncthreads();

        float tmp[4][4] = {{0.f, 0.f, 0.f, 0.f}, {0.f, 0.f, 0.f, 0.f},
                           {0.f, 0.f, 0.f, 0.f}, {0.f, 0.f, 0.f, 0.f}};
        #pragma unroll
        for (int kk = 0; kk < BK; ++kk) {
            float4 a = *(const float4*)&hsT[kk][tg << 2];
            float4 b = *(const float4*)&wT[kk][eg << 2];
            const float av0 = a.x, av1 = a.y, av2 = a.z, av3 = a.w;
            const float bv0 = b.x, bv1 = b.y, bv2 = b.z, bv3 = b.w;
            tmp[0][0] = fmaf(av0, bv0, tmp[0][0]);
            tmp[0][1] = fmaf(av0, bv1, tmp[0][1]);
            tmp[0][2] = fmaf(av0, bv2, tmp[0][2]);
            tmp[0][3] = fmaf(av0, bv3, tmp[0][3]);
            tmp[1][0] = fmaf(av1, bv0, tmp[1][0]);
            tmp[1][1] = fmaf(av1, bv1, tmp[1][1]);
            tmp[1][2] = fmaf(av1, bv2, tmp[1][2]);
            tmp[1][3] = fmaf(av1, bv3, tmp[1][3]);
            tmp[2][0] = fmaf(av2, bv0, tmp[2][0]);
            tmp[2][1] = fmaf(av2, bv1, tmp[2][1]);
            tmp[2][2] = fmaf(av2, bv2, tmp[2][2]);
            tmp[2][3] = fmaf(av2, bv3, tmp[2][3]);
            tmp[3][0] = fmaf(av3, bv0, tmp[3][0]);
            tmp[3][1] = fmaf(av3, bv1, tmp[3][1]);
            tmp[3][2] = fmaf(av3, bv2, tmp[3][2]);
            tmp[3][3] = fmaf(av3, bv3, tmp[3][3]);
        }
        #pragma unroll
        for (int i = 0; i < 4; ++i)
            #pragma unroll
            for (int j = 0; j < 4; ++j)
                acc[i][j] += tmp[i][j];
        __syncthreads();
    }

    float* pb = partial + ((size_t)bk * TOKENS + (size_t)bt * TM) * NEXP;
    #pragma unroll
    for (int i = 0; i < 4; ++i) {
        float4 v = make_float4(acc[i][0], acc[i][1], acc[i][2], acc[i][3]);
        *(float4*)&pb[(size_t)(tg * 4 + i) * NEXP + eg * 4] = v;
    }
}

// ---------------- Kernel 2: softmax + top-8 (+ f64 near-tie fixup) ----------
// One wave per token (lane-per-expert), 16 tokens per wave.
__global__ __launch_bounds__(256, 2) void router_epilogue(
    const float* __restrict__ hs, const float* __restrict__ w,
    const float* __restrict__ partial, float* __restrict__ scores,
    float* __restrict__ out_idx, int ksplit)
{
    const int lane = threadIdx.x & 63;
    const int wv   = threadIdx.x >> 6;   // wave 0..3
    const int tokBase = (blockIdx.x * 4 + wv) * 16;

    for (int it = 0; it < 16; ++it) {
        const int t = tokBase + it;

        // gather logit for (t, expert=lane)
        float L = 0.f;
        for (int s = 0; s < ksplit; ++s)
            L += partial[((size_t)s * TOKENS + t) * NEXP + lane];

        // f32 softmax scores (tolerance is loose)
        float m = L;
        for (int o = 32; o; o >>= 1) m = fmaxf(m, __shfl_xor(m, o));
        float p = __expf(L - m);
        float sum = p;
        for (int o = 32; o; o >>= 1) sum += __shfl_xor(sum, o);
        float score = p / sum;

        // top-9 selection with stable (low-index) tie-break; track min gap
        float cur = L;
        float prevv = 0.f, mingap = 1e30f, myidx = 0.f;
        #pragma unroll
        for (int r = 0; r < 9; ++r) {
            float v = cur;
            int   i = lane;
            for (int o = 32; o; o >>= 1) {
                float ov = __shfl_xor(v, o);
                int   oi = __shfl_xor(i, o);
                if (ov > v || (ov == v && oi < i)) { v = ov; i = oi; }
            }
            if (r > 0) mingap = fminf(mingap, prevv - v);
            prevv = v;
            if (r < 8 && lane == r) myidx = (float)i;
            if (lane == i) cur = -3.4e38f;
        }

        if (mingap < 1e-5f) {
            // near-tie: recompute this token's logits exactly (f64)
            double dL = 0.0;
            const float* hrow = hs + (size_t)t * HIDDEN;
            for (int e = 0; e < NEXP; ++e) {
                const float* wrow = w + (size_t)e * HIDDEN;
                double a = 0.0;
                for (int j = 0; j < HIDDEN / 64; ++j) {
                    const int k = j * 64 + lane;
                    a = fma((double)hrow[k], (double)wrow[k], a);
                }
                for (int o = 32; o; o >>= 1) a += __shfl_xor(a, o);
                if (lane == e) dL = a;
            }
            double dm = dL;
            for (int o = 32; o; o >>= 1) dm = fmax(dm, __shfl_xor(dm, o));
            float p2 = __expf((float)(dL - dm));
            float s2 = p2;
            for (int o = 32; o; o >>= 1) s2 += __shfl_xor(s2, o);
            score = p2 / s2;

            double cur2 = dL;
            #pragma unroll
            for (int r = 0; r < 8; ++r) {
                double v = cur2;
                int    i = lane;
                for (int o = 32; o; o >>= 1) {
                    double ov = __shfl_xor(v, o);
                    int    oi = __shfl_xor(i, o);
                    if (ov > v || (ov == v && oi < i)) { v = ov; i = oi; }
                }
                if (lane == r) myidx = (float)i;
                if (lane == i) cur2 = -1e300;
            }
        }

        scores[(size_t)t * NEXP + lane] = score;
        if (lane < TOPK) out_idx[(size_t)t * TOPK + lane] = myidx;
    }
}

// ---------------------------------------------------------------------------
extern "C" void kernel_launch(void* const* d_in, const int* in_sizes, int n_in,
                              void* d_out, int out_size, void* d_ws, size_t ws_size,
                              hipStream_t stream) {
    const float* hs = (const float*)d_in[0];
    const float* w  = (const float*)d_in[1];
    float* scores  = (float*)d_out;
    float* out_idx = (float*)d_out + (size_t)TOKENS * NEXP;

    const size_t planeBytes = (size_t)TOKENS * NEXP * sizeof(float); // 4 MB
    int ksplit;
    float* partial;
    if (ws_size >= 4 * planeBytes)      { ksplit = 4; partial = (float*)d_ws; }
    else if (ws_size >= 2 * planeBytes) { ksplit = 2; partial = (float*)d_ws; }
    else if (ws_size >= planeBytes)     { ksplit = 1; partial = (float*)d_ws; }
    else                                { ksplit = 1; partial = scores; } // in-place fallback

    dim3 g1(TOKENS / TM, ksplit);
    router_gemm<<<g1, 256, 0, stream>>>(hs, w, partial, ksplit);
    router_epilogue<<<TOKENS / TM, 256, 0, stream>>>(hs, w, partial, scores, out_idx, ksplit);
}

// Round 3
// 587.150 us; speedup vs baseline: 1.1533x; 1.1533x over previous
//
#include <hip/hip_runtime.h>
#include <math.h>

#define TOKENS 16384
#define HIDDEN 4096
#define NEXP   64
#define TOPK   8

#define TM  128          // tokens per block
#define BK  32           // K tile
#define LDH 132          // hsT padded row stride (floats)
#define LDW 68           // wT padded row stride

// ---------------- Kernel 1: tiled f32 GEMM -> partial logits ----------------
// grid: (TOKENS/TM) x ksplit, block 256. Per-thread 8 tokens x 4 experts.
__global__ __launch_bounds__(256, 4) void router_gemm(
    const float* __restrict__ hs, const float* __restrict__ w,
    float* __restrict__ partial, int ksplit)
{
    __shared__ float hsT[BK][LDH];   // [k][token]
    __shared__ float wT[BK][LDW];    // [k][expert]

    const int tid = threadIdx.x;
    const int bt  = blockIdx.x;
    const int bk  = blockIdx.y;
    const int kspan  = HIDDEN / ksplit;
    const int k0base = bk * kspan;

    const int tg = tid & 15;         // token group: tokens tg*8..tg*8+7
    const int eg = tid >> 4;         // expert group: experts eg*4..eg*4+3

    const int lrow = tid >> 3;       // 0..31 (staging row)
    const int lk4  = (tid & 7) * 4;  // staging k offset (float4)

    float acc[8][4];
    #pragma unroll
    for (int i = 0; i < 8; ++i)
        #pragma unroll
        for (int j = 0; j < 4; ++j) acc[i][j] = 0.f;

    const int ntiles = kspan / BK;
    for (int tile = 0; tile < ntiles; ++tile) {
        const int k0 = k0base + tile * BK;

        // stage hs tile (128 tok x 32 k), transposed
        #pragma unroll
        for (int p = 0; p < 4; ++p) {
            const int tok = lrow + p * 32;
            float4 hv = *(const float4*)&hs[(size_t)(bt * TM + tok) * HIDDEN + k0 + lk4];
            hsT[lk4 + 0][tok] = hv.x;
            hsT[lk4 + 1][tok] = hv.y;
            hsT[lk4 + 2][tok] = hv.z;
            hsT[lk4 + 3][tok] = hv.w;
        }
        // stage w tile (64 exp x 32 k), transposed
        #pragma unroll
        for (int p = 0; p < 2; ++p) {
            const int ex = lrow + p * 32;
            float4 wv = *(const float4*)&w[(size_t)ex * HIDDEN + k0 + lk4];
            wT[lk4 + 0][ex] = wv.x;
            wT[lk4 + 1][ex] = wv.y;
            wT[lk4 + 2][ex] = wv.z;
            wT[lk4 + 3][ex] = wv.w;
        }
        __syncthreads();

        #pragma unroll 8
        for (int kk = 0; kk < BK; ++kk) {
            float4 a0 = *(const float4*)&hsT[kk][tg * 8];
            float4 a1 = *(const float4*)&hsT[kk][tg * 8 + 4];
            float4 b  = *(const float4*)&wT[kk][eg * 4];
            const float av[8] = {a0.x, a0.y, a0.z, a0.w, a1.x, a1.y, a1.z, a1.w};
            const float bv[4] = {b.x, b.y, b.z, b.w};
            #pragma unroll
            for (int i = 0; i < 8; ++i)
                #pragma unroll
                for (int j = 0; j < 4; ++j)
                    acc[i][j] = fmaf(av[i], bv[j], acc[i][j]);
        }
        __syncthreads();
    }

    float* pb = partial + ((size_t)bk * TOKENS + (size_t)bt * TM) * NEXP;
    #pragma unroll
    for (int i = 0; i < 8; ++i) {
        float4 v = make_float4(acc[i][0], acc[i][1], acc[i][2], acc[i][3]);
        *(float4*)&pb[(size_t)(tg * 8 + i) * NEXP + eg * 4] = v;
    }
}

// ---------------- Kernel 2: softmax + top-8 (+ f64 near-tie fixup) ----------
// One wave per TOKEN (4 tokens/block). Rank-based top-k: no dependent
// shuffle chains; LDS broadcast + 64 parallel compares.
__global__ __launch_bounds__(256, 4) void router_epilogue(
    const float* __restrict__ hs, const float* __restrict__ w,
    const float* __restrict__ partial, float* __restrict__ scores,
    float* __restrict__ out_idx, int ksplit)
{
    __shared__ float sv[4][64];
    __shared__ float ssort[4][64];

    const int lane = threadIdx.x & 63;
    const int wv   = threadIdx.x >> 6;
    const int t    = blockIdx.x * 4 + wv;

    // gather logit for (t, expert=lane)
    float L = 0.f;
    for (int s = 0; s < ksplit; ++s)
        L += partial[((size_t)s * TOKENS + t) * NEXP + lane];

    // f32 softmax (tolerance is loose for scores)
    float m = L;
    for (int o = 32; o; o >>= 1) m = fmaxf(m, __shfl_xor(m, o));
    float p = __expf(L - m);
    float sum = p;
    for (int o = 32; o; o >>= 1) sum += __shfl_xor(sum, o);
    float score = p / sum;

    // rank = #{j: v_j > v_i} + #{j<i: v_j == v_i}  (stable low-index order)
    sv[wv][lane] = L;
    __syncthreads();
    int rank = 0;
    #pragma unroll 16
    for (int j = 0; j < 64; ++j) {
        float o = sv[wv][j];
        rank += (o > L) || (o == L && j < lane);
    }
    ssort[wv][rank] = L;   // ranks are unique -> full sorted array
    __syncthreads();

    float gap = 1e30f;
    if (lane < 8) gap = ssort[wv][lane] - ssort[wv][lane + 1];  // top-9 gaps
    const bool tie = __any(gap < 2e-5f);

    if (!tie) {
        if (rank < TOPK) out_idx[(size_t)t * TOPK + rank] = (float)lane;
    } else {
        // near-tie: recompute this token's logits exactly (f64)
        double dL = 0.0;
        const float* hrow = hs + (size_t)t * HIDDEN;
        for (int e = 0; e < NEXP; ++e) {
            const float* wrow = w + (size_t)e * HIDDEN;
            double a = 0.0;
            for (int j = 0; j < HIDDEN / 64; ++j) {
                const int k = j * 64 + lane;
                a = fma((double)hrow[k], (double)wrow[k], a);
            }
            for (int o = 32; o; o >>= 1) a += __shfl_xor(a, o);
            if (lane == e) dL = a;
        }
        double dm = dL;
        for (int o = 32; o; o >>= 1) dm = fmax(dm, __shfl_xor(dm, o));
        float p2 = __expf((float)(dL - dm));
        float s2 = p2;
        for (int o = 32; o; o >>= 1) s2 += __shfl_xor(s2, o);
        score = p2 / s2;

        double cur2 = dL;
        float myidx = 0.f;
        #pragma unroll
        for (int r = 0; r < 8; ++r) {
            double v = cur2;
            int    i = lane;
            for (int o = 32; o; o >>= 1) {
                double ov = __shfl_xor(v, o);
                int    oi = __shfl_xor(i, o);
                if (ov > v || (ov == v && oi < i)) { v = ov; i = oi; }
            }
            if (lane == r) myidx = (float)i;
            if (lane == i) cur2 = -1e300;
        }
        if (lane < TOPK) out_idx[(size_t)t * TOPK + lane] = myidx;
    }

    scores[(size_t)t * NEXP + lane] = score;
}

// ---------------------------------------------------------------------------
extern "C" void kernel_launch(void* const* d_in, const int* in_sizes, int n_in,
                              void* d_out, int out_size, void* d_ws, size_t ws_size,
                              hipStream_t stream) {
    const float* hs = (const float*)d_in[0];
    const float* w  = (const float*)d_in[1];
    float* scores  = (float*)d_out;
    float* out_idx = (float*)d_out + (size_t)TOKENS * NEXP;

    const size_t planeBytes = (size_t)TOKENS * NEXP * sizeof(float); // 4 MB
    int ksplit;
    float* partial;
    if      (ws_size >= 8 * planeBytes) { ksplit = 8; partial = (float*)d_ws; }
    else if (ws_size >= 4 * planeBytes) { ksplit = 4; partial = (float*)d_ws; }
    else if (ws_size >= 2 * planeBytes) { ksplit = 2; partial = (float*)d_ws; }
    else if (ws_size >= 1 * planeBytes) { ksplit = 1; partial = (float*)d_ws; }
    else                                { ksplit = 1; partial = scores; }

    dim3 g1(TOKENS / TM, ksplit);
    router_gemm<<<g1, 256, 0, stream>>>(hs, w, partial, ksplit);
    router_epilogue<<<TOKENS / 4, 256, 0, stream>>>(hs, w, partial, scores, out_idx, ksplit);
}

// Round 5
// 456.579 us; speedup vs baseline: 1.4831x; 1.2860x over previous
//
#include <hip/hip_runtime.h>
#include <hip/hip_bf16.h>
#include <math.h>

#define TOKENS 16384
#define HIDDEN 4096
#define NEXP   64
#define TOPK   8

#define BT   64     // tokens per gemm block
#define BK   32     // K per MFMA step
#define LDSS 40     // LDS row stride in shorts (80 B: 16B-aligned, 2-way max)
#define MAXTIE 8190

typedef short s16x8 __attribute__((ext_vector_type(8)));
typedef float f32x4 __attribute__((ext_vector_type(4)));

__device__ inline unsigned short bf16_rne(float x) {
    unsigned u = __builtin_bit_cast(unsigned, x);
    unsigned r = (u + 0x7FFFu + ((u >> 16) & 1u)) >> 16;
    return (unsigned short)r;
}
__device__ inline float bf16_f32(unsigned short h) {
    unsigned u = ((unsigned)h) << 16;
    return __builtin_bit_cast(float, u);
}

// ---- Kernel 0: split w into bf16 limb planes; zero tie counter ------------
__global__ void conv_w(const float* __restrict__ w,
                       unsigned short* __restrict__ whi,
                       unsigned short* __restrict__ wlo,
                       int* __restrict__ tiecnt) {
    if (blockIdx.x == 0 && threadIdx.x == 0) *tiecnt = 0;
    const int i = (blockIdx.x * 256 + threadIdx.x) * 4;  // 262144 elems total
    float4 v = *(const float4*)&w[i];
    float xv[4] = {v.x, v.y, v.z, v.w};
    ushort4 h, l;
    unsigned short* hp = &h.x;
    unsigned short* lp = &l.x;
    #pragma unroll
    for (int j = 0; j < 4; ++j) {
        unsigned short hb = bf16_rne(xv[j]);
        hp[j] = hb;
        lp[j] = bf16_rne(xv[j] - bf16_f32(hb));
    }
    *(ushort4*)&whi[i] = h;
    *(ushort4*)&wlo[i] = l;
}

// ---- Kernel 1: 4-limb bf16 MFMA GEMM -> partial logits --------------------
// grid (TOKENS/BT, ksplit), block 256 (4 waves). Wave computes 32 tok x 32 exp
// (2x2 tiles of 16x16x32 MFMA, 4 limb combos each).
__global__ __launch_bounds__(256, 2) void router_gemm(
    const float* __restrict__ hs, const unsigned short* __restrict__ whi,
    const unsigned short* __restrict__ wlo, float* __restrict__ partial,
    int ksplit)
{
    __shared__ short Ah[BT * LDSS];
    __shared__ short Al[BT * LDSS];
    __shared__ short Bh[NEXP * LDSS];
    __shared__ short Bl[NEXP * LDSS];

    const int tid  = threadIdx.x;
    const int btok = blockIdx.x * BT;
    const int bk   = blockIdx.y;
    const int kspan  = HIDDEN / ksplit;
    const int k0base = bk * kspan;

    const int lane = tid & 63;
    const int wv   = tid >> 6;
    const int wtok = (wv & 1) * 32;
    const int wexp = (wv >> 1) * 32;
    const int r16  = lane & 15;
    const int q4   = lane >> 4;      // 0..3

    const int srow = tid >> 2;       // 0..63 staging row
    const int sk8  = (tid & 3) * 8;  // 0,8,16,24

    f32x4 acc[2][2] = {};

    const int ntiles = kspan / BK;
    for (int kt = 0; kt < ntiles; ++kt) {
        const int k0 = k0base + kt * BK;

        // stage A (hs f32 -> hi/lo bf16 limbs)
        float4 a0 = *(const float4*)&hs[(size_t)(btok + srow) * HIDDEN + k0 + sk8];
        float4 a1 = *(const float4*)&hs[(size_t)(btok + srow) * HIDDEN + k0 + sk8 + 4];
        float xv[8] = {a0.x, a0.y, a0.z, a0.w, a1.x, a1.y, a1.z, a1.w};
        s16x8 hv, lv;
        #pragma unroll
        for (int j = 0; j < 8; ++j) {
            unsigned short hb = bf16_rne(xv[j]);
            hv[j] = (short)hb;
            lv[j] = (short)bf16_rne(xv[j] - bf16_f32(hb));
        }
        *(s16x8*)&Ah[srow * LDSS + sk8] = hv;
        *(s16x8*)&Al[srow * LDSS + sk8] = lv;

        // stage B (precomputed limb planes, straight copy)
        s16x8 bh = *(const s16x8*)&whi[(size_t)srow * HIDDEN + k0 + sk8];
        s16x8 bl = *(const s16x8*)&wlo[(size_t)srow * HIDDEN + k0 + sk8];
        *(s16x8*)&Bh[srow * LDSS + sk8] = bh;
        *(s16x8*)&Bl[srow * LDSS + sk8] = bl;
        __syncthreads();

        s16x8 afh[2], afl[2], bfh[2], bfl[2];
        #pragma unroll
        for (int tt = 0; tt < 2; ++tt) {
            const int row = wtok + tt * 16 + r16;
            afh[tt] = *(const s16x8*)&Ah[row * LDSS + q4 * 8];
            afl[tt] = *(const s16x8*)&Al[row * LDSS + q4 * 8];
        }
        #pragma unroll
        for (int et = 0; et < 2; ++et) {
            const int row = wexp + et * 16 + r16;
            bfh[et] = *(const s16x8*)&Bh[row * LDSS + q4 * 8];
            bfl[et] = *(const s16x8*)&Bl[row * LDSS + q4 * 8];
        }
        #pragma unroll
        for (int tt = 0; tt < 2; ++tt)
            #pragma unroll
            for (int et = 0; et < 2; ++et) {
                acc[tt][et] = __builtin_amdgcn_mfma_f32_16x16x32_bf16(afh[tt], bfh[et], acc[tt][et], 0, 0, 0);
                acc[tt][et] = __builtin_amdgcn_mfma_f32_16x16x32_bf16(afl[tt], bfh[et], acc[tt][et], 0, 0, 0);
                acc[tt][et] = __builtin_amdgcn_mfma_f32_16x16x32_bf16(afh[tt], bfl[et], acc[tt][et], 0, 0, 0);
                acc[tt][et] = __builtin_amdgcn_mfma_f32_16x16x32_bf16(afl[tt], bfl[et], acc[tt][et], 0, 0, 0);
            }
        __syncthreads();
    }

    // C/D layout (guide-verified): col = lane&15, row = (lane>>4)*4 + reg
    float* pb = partial + (size_t)bk * TOKENS * NEXP;
    #pragma unroll
    for (int tt = 0; tt < 2; ++tt)
        #pragma unroll
        for (int et = 0; et < 2; ++et)
            #pragma unroll
            for (int r = 0; r < 4; ++r) {
                const int row = btok + wtok + tt * 16 + q4 * 4 + r;
                const int col = wexp + et * 16 + r16;
                pb[(size_t)row * NEXP + col] = acc[tt][et][r];
            }
}

// ---- Kernel 2: softmax + rank top-8; ties -> list -------------------------
__global__ __launch_bounds__(256, 4) void router_epilogue(
    const float* __restrict__ partial, float* __restrict__ scores,
    float* __restrict__ out_idx, int ksplit,
    int* __restrict__ tiecnt, int* __restrict__ tielist)
{
    __shared__ float sv[4][64];
    __shared__ float ssort[4][64];

    const int lane = threadIdx.x & 63;
    const int wv   = threadIdx.x >> 6;
    const int t    = blockIdx.x * 4 + wv;

    float L = 0.f;
    for (int s = 0; s < ksplit; ++s)
        L += partial[((size_t)s * TOKENS + t) * NEXP + lane];

    float m = L;
    for (int o = 32; o; o >>= 1) m = fmaxf(m, __shfl_xor(m, o));
    float p = __expf(L - m);
    float sum = p;
    for (int o = 32; o; o >>= 1) sum += __shfl_xor(sum, o);
    scores[(size_t)t * NEXP + lane] = p / sum;

    sv[wv][lane] = L;
    __syncthreads();
    int rank = 0;
    #pragma unroll 16
    for (int j = 0; j < 64; ++j) {
        float o = sv[wv][j];
        rank += (o > L) || (o == L && j < lane);
    }
    ssort[wv][rank] = L;
    __syncthreads();

    float gap = 1e30f;
    if (lane < 8) gap = ssort[wv][lane] - ssort[wv][lane + 1];
    if (rank < TOPK) out_idx[(size_t)t * TOPK + rank] = (float)lane;

    if (__any(gap < 1e-5f) && lane == 0) {
        int pidx = atomicAdd(tiecnt, 1);
        if (pidx < MAXTIE) tielist[pidx] = t;
    }
}

// ---- Kernel 3: parallel f64 fixup for near-tie tokens ---------------------
__global__ __launch_bounds__(256, 2) void router_fixup(
    const float* __restrict__ hs, const float* __restrict__ w,
    float* __restrict__ scores, float* __restrict__ out_idx,
    const int* __restrict__ tiecnt, const int* __restrict__ tielist)
{
    __shared__ double dlog[NEXP];
    int n = *tiecnt;
    if (n > MAXTIE) n = MAXTIE;
    const int lane = threadIdx.x & 63;
    const int wv   = threadIdx.x >> 6;

    for (int i = blockIdx.x; i < n; i += gridDim.x) {
        const int t = tielist[i];
        const float* hrow = hs + (size_t)t * HIDDEN;
        for (int e8 = 0; e8 < 16; ++e8) {
            const int e = wv * 16 + e8;
            const float* wrow = w + (size_t)e * HIDDEN;
            double a0 = 0, a1 = 0, a2 = 0, a3 = 0;
            #pragma unroll 4
            for (int j = 0; j < 64; j += 4) {
                a0 = fma((double)hrow[(j + 0) * 64 + lane], (double)wrow[(j + 0) * 64 + lane], a0);
                a1 = fma((double)hrow[(j + 1) * 64 + lane], (double)wrow[(j + 1) * 64 + lane], a1);
                a2 = fma((double)hrow[(j + 2) * 64 + lane], (double)wrow[(j + 2) * 64 + lane], a2);
                a3 = fma((double)hrow[(j + 3) * 64 + lane], (double)wrow[(j + 3) * 64 + lane], a3);
            }
            double a = (a0 + a1) + (a2 + a3);
            for (int o = 32; o; o >>= 1) a += __shfl_xor(a, o);
            if (lane == 0) dlog[e] = a;
        }
        __syncthreads();
        if (wv == 0) {
            const double L = dlog[lane];
            double m = L;
            for (int o = 32; o; o >>= 1) m = fmax(m, __shfl_xor(m, o));
            double p = exp(L - m);
            double s = p;
            for (int o = 32; o; o >>= 1) s += __shfl_xor(s, o);
            scores[(size_t)t * NEXP + lane] = (float)(p / s);
            int rank = 0;
            for (int j = 0; j < 64; ++j) {
                double o = dlog[j];
                rank += (o > L) || (o == L && j < lane);
            }
            if (rank < TOPK) out_idx[(size_t)t * TOPK + rank] = (float)lane;
        }
        __syncthreads();
    }
}

// ---------------------------------------------------------------------------
extern "C" void kernel_launch(void* const* d_in, const int* in_sizes, int n_in,
                              void* d_out, int out_size, void* d_ws, size_t ws_size,
                              hipStream_t stream) {
    const float* hs = (const float*)d_in[0];
    const float* w  = (const float*)d_in[1];
    float* scores  = (float*)d_out;
    float* out_idx = (float*)d_out + (size_t)TOKENS * NEXP;

    const size_t planeElems = (size_t)TOKENS * NEXP;          // 1M floats = 4 MB
    const size_t wElems     = (size_t)NEXP * HIDDEN;          // 256K
    const size_t tailBytes  = wElems * 4 + (MAXTIE + 2) * 4;  // limb planes + list

    int ksplit = 4;
    while (ksplit > 1 && ws_size < ksplit * planeElems * 4 + tailBytes) ksplit >>= 1;

    float* partial        = (float*)d_ws;
    unsigned short* whi   = (unsigned short*)(partial + ksplit * planeElems);
    unsigned short* wlo   = whi + wElems;
    int* tiecnt           = (int*)(wlo + wElems);
    int* tielist          = tiecnt + 1;

    conv_w<<<wElems / 1024, 256, 0, stream>>>(w, whi, wlo, tiecnt);
    dim3 g1(TOKENS / BT, ksplit);
    router_gemm<<<g1, 256, 0, stream>>>(hs, whi, wlo, partial, ksplit);
    router_epilogue<<<TOKENS / 4, 256, 0, stream>>>(partial, scores, out_idx,
                                                    ksplit, tiecnt, tielist);
    router_fixup<<<128, 256, 0, stream>>>(hs, w, scores, out_idx, tiecnt, tielist);
}